// Round 3
// baseline (365.267 us; speedup 1.0000x reference)
//
#include <hip/hip_runtime.h>
#include <stdint.h>
#include <math.h>

// numpy never fuses a*a+s into fma; explicit __builtin_fmaf still emits fma.
#pragma clang fp contract(off)

// Problem constants
#define B_   64
#define C_   64
#define HW_  1024
#define K_   512
#define N_   65536   // B_*HW_

// Output layout (float element offsets into d_out, reference return order)
#define OUT_Q    0ull                  // [B,C,H,W]  4194304
#define OUT_LOSS 4194304ull            // [B]        64
#define OUT_PERP 4194368ull            // scalar     1
#define OUT_ENC  4194369ull            // [N,K]      33554432
#define OUT_IDX  37748801ull           // [B,HW]     65536
#define OUT_DIST 37814337ull           // [N,K]      33554432

// Workspace layout (bytes)
#define WS_WT     0ull        // float[64*512]   wt[c][k]      (q_out gather)
#define WS_WT2    131072ull   // float[64*512]   swizzled: [cc][cl][lane][j]
#define WS_WNORM  262144ull   // float[512]
#define WS_SUMSQ  264192ull   // float[64]

// ---------------------------------------------------------------------------
// Prep: wt[c*512+k] = w[k*64+c];
//       wt2[(c>>4)*8192 + (c&15)*512 + (k&63)*8 + (k>>6)] = w[k*64+c]
//       (so main can stage contiguous 32 KB chunks and read each lane's 8
//        k-values {l+64j} as two contiguous ds_read_b128)
//       wnorm[k] = numpy-pairwise sum of w[k,:]^2; sumsq zeroed here.
// ---------------------------------------------------------------------------
__global__ __launch_bounds__(256) void vq_prep(const float* __restrict__ w,
                                               float* __restrict__ wt,
                                               float* __restrict__ wt2,
                                               float* __restrict__ wnorm,
                                               float* __restrict__ sumsq) {
  const int t = threadIdx.x;
  const int g = blockIdx.x * 256 + t;          // 0..32767
  const int c = g >> 9;
  const int k = g & 511;
  const float v = w[k * 64 + c];
  wt[g] = v;
  wt2[(c >> 4) * 8192 + (c & 15) * 512 + (k & 63) * 8 + (k >> 6)] = v;

  if (blockIdx.x == 0 && t < 64) sumsq[t] = 0.f;

  if (blockIdx.x < 16) {                       // 4096 threads = 512 rows x 8
    const int row = g >> 3;
    const int j = g & 7;
    float s = 0.f;
    for (int i = 0; i < 8; ++i) {
      float vv = w[row * 64 + 8 * i + j];
      float sq = vv * vv;                      // rounded square (no fma fuse)
      s = s + sq;
    }
    float o1 = __shfl_xor(s, 1); s = s + o1;   // numpy 8-acc combine tree
    float o2 = __shfl_xor(s, 2); s = s + o2;
    float o4 = __shfl_xor(s, 4); s = s + o4;
    if (j == 0) wnorm[row] = s;
  }
}

// ---------------------------------------------------------------------------
// Main: one block = 32 rows. Wave w owns rows 8w..8w+7; lane l owns k=l+64j.
// K-loop reads: wv = 2x ds_read_b128 (swizzled layout), xv = wave-uniform
// global float4 loads (L1 broadcast) — no per-cl LDS broadcasts.
// ---------------------------------------------------------------------------
__global__ __launch_bounds__(256, 3) void vq_main(const float* __restrict__ x,
                                                  const float* __restrict__ wt,
                                                  const float* __restrict__ wt2,
                                                  const float* __restrict__ wnorm,
                                                  float* __restrict__ out,
                                                  float* __restrict__ sumsq) {
  __shared__ float x_s[64 * 32];    // [c][m]
  __shared__ float w_s[16 * 512];   // one 32 KB swizzled chunk of wt2
  __shared__ float wn_s[512];
  __shared__ float an_s[32];
  __shared__ int   kmin_s[32];
  __shared__ float red_s[4];

  const int t   = threadIdx.x;
  const int blk = blockIdx.x;       // 0..2047
  const int n0  = blk * 32;
  const int b   = n0 >> 10;
  const int hw0 = n0 & 1023;
  const int wid = t >> 6;           // wave 0..3
  const int l   = t & 63;

  // ---- stage x tile: x_s[c][m] = x[b, c, hw0+m] ----
  {
    const float* xb = x + (size_t)b * 65536 + hw0;
    const int c0 = t >> 3;          // 0..31
    const int m4 = (t & 7) * 4;
    for (int i = 0; i < 2; ++i) {
      int c = i * 32 + c0;
      float4 v = *(const float4*)(xb + (size_t)c * 1024 + m4);
      *(float4*)(&x_s[c * 32 + m4]) = v;
    }
  }
  wn_s[t] = wnorm[t];
  wn_s[t + 256] = wnorm[t + 256];
  __syncthreads();

  // ---- a_n = ||x_row||^2, exact numpy pairwise tree (8 lanes/row) ----
  {
    const int r = t >> 3, j = t & 7;
    float s = 0.f;
    for (int i = 0; i < 8; ++i) {
      float v = x_s[(8 * i + j) * 32 + r];
      float sq = v * v;
      s = s + sq;
    }
    float o1 = __shfl_xor(s, 1); s = s + o1;
    float o2 = __shfl_xor(s, 2); s = s + o2;
    float o4 = __shfl_xor(s, 4); s = s + o4;
    if (j == 0) an_s[r] = s;
  }

  float wn[8];
  for (int j = 0; j < 8; ++j) wn[j] = wn_s[l + 64 * j];

  // wave-uniform base for this wave's 8 rows in x (NCHW: [c][hw])
  const int uwid = __builtin_amdgcn_readfirstlane(wid);
  const float* xrow = x + (size_t)b * 65536 + (size_t)(hw0 + 8 * uwid);

  // ---- dots: acc[i][j] = x_row(8*wid+i) . w_col(l+64j), c ascending fma ----
  float acc[8][8];
  for (int i = 0; i < 8; ++i)
    for (int j = 0; j < 8; ++j) acc[i][j] = 0.f;

#pragma unroll 1
  for (int cc = 0; cc < 4; ++cc) {
    __syncthreads();                 // protect w_s from previous chunk use
    for (int i = 0; i < 8; ++i) {    // contiguous 32 KB copy (swizzle is baked)
      int f4 = i * 256 + t;
      *(float4*)(&w_s[f4 * 4]) = *(const float4*)(wt2 + (size_t)cc * 8192 + f4 * 4);
    }
    __syncthreads();
#pragma unroll
    for (int cl = 0; cl < 16; ++cl) {
      const float* xp = xrow + (size_t)(cc * 16 + cl) * 1024;
      float xv[8];
      *(float4*)(xv)     = *(const float4*)(xp);       // uniform → L1 broadcast
      *(float4*)(xv + 4) = *(const float4*)(xp + 4);
      float wv[8];
      *(float4*)(wv)     = *(const float4*)(&w_s[cl * 512 + l * 8]);     // b128
      *(float4*)(wv + 4) = *(const float4*)(&w_s[cl * 512 + l * 8 + 4]); // b128
      for (int i = 0; i < 8; ++i)
        for (int j = 0; j < 8; ++j)
          acc[i][j] = __builtin_fmaf(xv[i], wv[j], acc[i][j]);
    }
  }

  // ---- distances, argmin, encodings, enc_idx ----
  float* const dist_o = out + OUT_DIST;
  float* const enc_o  = out + OUT_ENC;
  const int m_base = 8 * wid;
  for (int i = 0; i < 8; ++i) {
    const int m = m_base + i;
    const size_t n = (size_t)(n0 + m);
    const float an = an_s[m];
    float D[8];
    for (int j = 0; j < 8; ++j) {
      float tt = an + wn[j];                       // fl(a+b), numpy order
      D[j] = __builtin_fmaf(-2.f, acc[i][j], tt);  // fl(t - 2*dot), exact 2x
    }
    float vb = D[0]; int kb = l;
    for (int j = 1; j < 8; ++j) {
      if (D[j] < vb) { vb = D[j]; kb = l + 64 * j; }
    }
    for (int d = 1; d < 64; d <<= 1) {             // ties -> lowest k
      float v2 = __shfl_xor(vb, d);
      int   k2 = __shfl_xor(kb, d);
      if (v2 < vb || (v2 == vb && k2 < kb)) { vb = v2; kb = k2; }
    }
    const size_t rb = n * 512 + l;
    for (int j = 0; j < 8; ++j) dist_o[rb + 64 * j] = D[j];              // coalesced
    for (int j = 0; j < 8; ++j) enc_o[rb + 64 * j] = (l + 64 * j == kb) ? 1.f : 0.f;
    if (l == i) {
      out[OUT_IDX + n] = (float)kb;
      kmin_s[m] = kb;
    }
  }
  __syncthreads();   // kmin_s visible to all waves

  // ---- q_out (NCHW) + per-batch loss partial ----
  float lsum = 0.f;
  float* const q_o = out + OUT_Q;
  for (int it = 0; it < 8; ++it) {
    const int idx8 = it * 256 + t;
    const int c = idx8 >> 5, m = idx8 & 31;
    const int kb = kmin_s[m];
    const float qv = wt[(size_t)c * 512 + kb];   // L1/L2-cached gather
    const float xv = x_s[c * 32 + m];
    const float d = qv - xv;
    lsum = __builtin_fmaf(d, d, lsum);
    q_o[(size_t)b * 65536 + (size_t)c * 1024 + (hw0 + m)] = qv;  // coalesced
  }
  for (int d = 1; d < 64; d <<= 1) lsum += __shfl_xor(lsum, d);
  if (l == 0) red_s[wid] = lsum;
  __syncthreads();
  if (t == 0) {
    float s = (red_s[0] + red_s[1]) + (red_s[2] + red_s[3]);
    atomicAdd(sumsq + b, s);
  }
}

// ---------------------------------------------------------------------------
// Finalize: histogram rebuilt from OUT_IDX (identical integer counts to an
// atomic hist); perplexity (double, same as passing R2); loss[b].
// ---------------------------------------------------------------------------
__global__ __launch_bounds__(1024) void vq_fin(float* __restrict__ out,
                                               const float* __restrict__ sumsq) {
  __shared__ int h4[4 * 512];
  __shared__ double red[8];
  const int t = threadIdx.x;
  h4[t] = 0; h4[t + 1024] = 0;
  __syncthreads();
  const float* idxp = out + OUT_IDX;
  int* const myh = &h4[(t & 3) * 512];
  for (int i = t; i < 65536; i += 1024) {
    int k = (int)idxp[i];
    atomicAdd(&myh[k], 1);
  }
  __syncthreads();
  if (t < 512) {
    int cnt = h4[t] + h4[512 + t] + h4[1024 + t] + h4[1536 + t];
    double p = (double)cnt * (1.0 / 65536.0);
    double term = p * log(p + 1e-10);
    for (int d = 1; d < 64; d <<= 1) term += __shfl_xor(term, d);
    if ((t & 63) == 0) red[t >> 6] = term;
  }
  __syncthreads();
  if (t == 0) {
    double s = 0.0;
    for (int i = 0; i < 8; ++i) s += red[i];
    out[OUT_PERP] = (float)exp(-s);
  }
  if (t < 64) {
    float m = sumsq[t] * (1.0f / 65536.0f);   // exact /2^16
    out[OUT_LOSS + t] = m + 0.25f * m;        // fl(m + fl(0.25m)), numpy order
  }
}

// ---------------------------------------------------------------------------
extern "C" void kernel_launch(void* const* d_in, const int* in_sizes, int n_in,
                              void* d_out, int out_size, void* d_ws, size_t ws_size,
                              hipStream_t stream) {
  const float* x = (const float*)d_in[0];   // [B,C,H,W] fp32
  const float* w = (const float*)d_in[1];   // [K,C] fp32
  float* out = (float*)d_out;
  char* ws = (char*)d_ws;
  float* wt    = (float*)(ws + WS_WT);
  float* wt2   = (float*)(ws + WS_WT2);
  float* wnorm = (float*)(ws + WS_WNORM);
  float* sumsq = (float*)(ws + WS_SUMSQ);

  vq_prep<<<128, 256, 0, stream>>>(w, wt, wt2, wnorm, sumsq);
  vq_main<<<2048, 256, 0, stream>>>(x, wt, wt2, wnorm, out, sumsq);
  vq_fin<<<1, 1024, 0, stream>>>(out, sumsq);
}

// Round 4
// 358.711 us; speedup vs baseline: 1.0183x; 1.0183x over previous
//
#include <hip/hip_runtime.h>
#include <stdint.h>
#include <math.h>

// numpy never fuses a*a+s into fma; explicit __builtin_fmaf still emits fma.
#pragma clang fp contract(off)

// Output layout (float element offsets into d_out, reference return order)
#define OUT_Q    0ull                  // [B,C,H,W]  4194304
#define OUT_LOSS 4194304ull            // [B]        64
#define OUT_PERP 4194368ull            // scalar     1
#define OUT_ENC  4194369ull            // [N,K]      33554432
#define OUT_IDX  37748801ull           // [B,HW]     65536
#define OUT_DIST 37814337ull           // [N,K]      33554432

// Workspace layout (bytes)
#define WS_WT2    0ull        // float[64*512]  swizzled: [cc][cl][lane][j]
#define WS_WNORM  131072ull   // float[512]
#define WS_SUMSQ  133120ull   // float[64]

// ---------------------------------------------------------------------------
// Prep: wt2[(c>>4)*8192 + (c&15)*512 + (k&63)*8 + (k>>6)] = w[k*64+c]
//       (main stages contiguous 32 KB chunks; lane's 8 k-values {l+64j} are
//        two contiguous ds_read_b128)
//       wnorm[k] = numpy-pairwise sum of w[k,:]^2; sumsq zeroed here.
// ---------------------------------------------------------------------------
__global__ __launch_bounds__(256) void vq_prep(const float* __restrict__ w,
                                               float* __restrict__ wt2,
                                               float* __restrict__ wnorm,
                                               float* __restrict__ sumsq) {
  const int t = threadIdx.x;
  const int g = blockIdx.x * 256 + t;          // 0..32767
  const int c = g >> 9;
  const int k = g & 511;
  wt2[(c >> 4) * 8192 + (c & 15) * 512 + (k & 63) * 8 + (k >> 6)] = w[k * 64 + c];

  if (blockIdx.x == 0 && t < 64) sumsq[t] = 0.f;

  if (blockIdx.x < 16) {                       // 4096 threads = 512 rows x 8
    const int row = g >> 3;
    const int j = g & 7;
    float s = 0.f;
    for (int i = 0; i < 8; ++i) {
      float vv = w[row * 64 + 8 * i + j];
      float sq = vv * vv;                      // rounded square (no fma fuse)
      s = s + sq;
    }
    float o1 = __shfl_xor(s, 1); s = s + o1;   // numpy 8-acc combine tree
    float o2 = __shfl_xor(s, 2); s = s + o2;
    float o4 = __shfl_xor(s, 4); s = s + o4;
    if (j == 0) wnorm[row] = s;
  }
}

// ---------------------------------------------------------------------------
// Main: one block = 32 rows. Wave w owns rows 8w..8w+7; lane l owns k=l+64j.
// K-loop: xv = 2x ds_read_b128 broadcast from x_s, wv = 2x ds_read_b128 from
// swizzled chunk. No global loads in the hot loop. Epilogue q_out uses
// coalesced w-row loads (kb is wave-uniform) staged through LDS (pool reuse).
// ---------------------------------------------------------------------------
__global__ __launch_bounds__(256, 3) void vq_main(const float* __restrict__ x,
                                                  const float* __restrict__ w,
                                                  const float* __restrict__ wt2,
                                                  const float* __restrict__ wnorm,
                                                  float* __restrict__ out,
                                                  float* __restrict__ sumsq) {
  __shared__ float x_s[64 * 32];    // [c][m]
  __shared__ float pool[16 * 512];  // K-loop: 32 KB wt2 chunk; after: q_s[32][65]
  __shared__ float wn_s[512];
  __shared__ float an_s[32];
  __shared__ float red_s[4];

  const int t   = threadIdx.x;
  const int blk = blockIdx.x;       // 0..2047
  const int n0  = blk * 32;
  const int b   = n0 >> 10;
  const int hw0 = n0 & 1023;
  const int wid = t >> 6;           // wave 0..3
  const int l   = t & 63;

  // ---- stage x tile: x_s[c][m] = x[b, c, hw0+m] ----
  {
    const float* xb = x + (size_t)b * 65536 + hw0;
    const int c0 = t >> 3;          // 0..31
    const int m4 = (t & 7) * 4;
    for (int i = 0; i < 2; ++i) {
      int c = i * 32 + c0;
      float4 v = *(const float4*)(xb + (size_t)c * 1024 + m4);
      *(float4*)(&x_s[c * 32 + m4]) = v;
    }
  }
  wn_s[t] = wnorm[t];
  wn_s[t + 256] = wnorm[t + 256];
  __syncthreads();

  // ---- a_n = ||x_row||^2, exact numpy pairwise tree (8 lanes/row) ----
  {
    const int r = t >> 3, j = t & 7;
    float s = 0.f;
    for (int i = 0; i < 8; ++i) {
      float v = x_s[(8 * i + j) * 32 + r];
      float sq = v * v;
      s = s + sq;
    }
    float o1 = __shfl_xor(s, 1); s = s + o1;
    float o2 = __shfl_xor(s, 2); s = s + o2;
    float o4 = __shfl_xor(s, 4); s = s + o4;
    if (j == 0) an_s[r] = s;
  }

  float wn[8];
  for (int j = 0; j < 8; ++j) wn[j] = wn_s[l + 64 * j];

  // ---- dots: acc[i][j] = x_row(8*wid+i) . w_col(l+64j), c ascending fma ----
  float acc[8][8];
  for (int i = 0; i < 8; ++i)
    for (int j = 0; j < 8; ++j) acc[i][j] = 0.f;

#pragma unroll 1
  for (int cc = 0; cc < 4; ++cc) {
    __syncthreads();                 // protect pool from previous chunk use
    for (int i = 0; i < 8; ++i) {    // contiguous 32 KB copy (swizzle baked in)
      int f4 = i * 256 + t;
      *(float4*)(&pool[f4 * 4]) = *(const float4*)(wt2 + (size_t)cc * 8192 + f4 * 4);
    }
    __syncthreads();
#pragma unroll
    for (int cl = 0; cl < 16; ++cl) {
      const float* xp = &x_s[(cc * 16 + cl) * 32 + 8 * wid];   // wave-uniform
      float xv[8];
      *(float4*)(xv)     = *(const float4*)(xp);        // LDS b128 broadcast
      *(float4*)(xv + 4) = *(const float4*)(xp + 4);
      float wv[8];
      *(float4*)(wv)     = *(const float4*)(&pool[cl * 512 + l * 8]);     // b128
      *(float4*)(wv + 4) = *(const float4*)(&pool[cl * 512 + l * 8 + 4]); // b128
      for (int i = 0; i < 8; ++i)
        for (int j = 0; j < 8; ++j)
          acc[i][j] = __builtin_fmaf(xv[i], wv[j], acc[i][j]);
    }
  }
  __syncthreads();                   // all waves done with pool -> becomes q_s
  float* const q_s = pool;           // [32][65] padded

  // ---- distances, argmin, encodings, enc_idx, q_s row fill ----
  float* const dist_o = out + OUT_DIST;
  float* const enc_o  = out + OUT_ENC;
  const int m_base = 8 * wid;
  for (int i = 0; i < 8; ++i) {
    const int m = m_base + i;
    const size_t n = (size_t)(n0 + m);
    const float an = an_s[m];
    float D[8];
    for (int j = 0; j < 8; ++j) {
      float tt = an + wn[j];                       // fl(a+b), numpy order
      D[j] = __builtin_fmaf(-2.f, acc[i][j], tt);  // fl(t - 2*dot), exact 2x
    }
    float vb = D[0]; int kb = l;
    for (int j = 1; j < 8; ++j) {
      if (D[j] < vb) { vb = D[j]; kb = l + 64 * j; }
    }
    for (int d = 1; d < 64; d <<= 1) {             // ties -> lowest k
      float v2 = __shfl_xor(vb, d);
      int   k2 = __shfl_xor(kb, d);
      if (v2 < vb || (v2 == vb && k2 < kb)) { vb = v2; kb = k2; }
    }
    const size_t rb = n * 512 + l;
    for (int j = 0; j < 8; ++j)                    // coalesced, streaming
      __builtin_nontemporal_store(D[j], &dist_o[rb + 64 * j]);
    for (int j = 0; j < 8; ++j)
      __builtin_nontemporal_store((l + 64 * j == kb) ? 1.f : 0.f,
                                  &enc_o[rb + 64 * j]);
    if (l == i) out[OUT_IDX + n] = (float)kb;
    // kb is wave-uniform: coalesced 256 B codebook-row load -> LDS
    q_s[m * 65 + l] = w[(size_t)kb * 64 + l];
  }
  __syncthreads();   // q_s complete

  // ---- q_out (NCHW, float4) + per-batch loss partial ----
  float lsum = 0.f;
  float* const q_o = out + OUT_Q;
  {
    const int c0 = t >> 3;          // 0..31
    const int m4 = (t & 7) * 4;
    for (int h = 0; h < 2; ++h) {
      const int c = h * 32 + c0;
      float qv[4];
      for (int e = 0; e < 4; ++e) qv[e] = q_s[(m4 + e) * 65 + c];
      float4 xv4 = *(const float4*)(&x_s[c * 32 + m4]);
      const float xe[4] = {xv4.x, xv4.y, xv4.z, xv4.w};
      for (int e = 0; e < 4; ++e) {
        float d = qv[e] - xe[e];
        lsum = __builtin_fmaf(d, d, lsum);
      }
      float4 qv4 = {qv[0], qv[1], qv[2], qv[3]};
      *(float4*)(&q_o[(size_t)b * 65536 + (size_t)c * 1024 + (hw0 + m4)]) = qv4;
    }
  }
  for (int d = 1; d < 64; d <<= 1) lsum += __shfl_xor(lsum, d);
  if (l == 0) red_s[wid] = lsum;
  __syncthreads();
  if (t == 0) {
    float s = (red_s[0] + red_s[1]) + (red_s[2] + red_s[3]);
    atomicAdd(sumsq + b, s);
  }
}

// ---------------------------------------------------------------------------
// Finalize: histogram rebuilt from OUT_IDX (identical integer counts to an
// atomic hist); perplexity in double; loss[b].
// ---------------------------------------------------------------------------
__global__ __launch_bounds__(1024) void vq_fin(float* __restrict__ out,
                                               const float* __restrict__ sumsq) {
  __shared__ int h4[4 * 512];
  __shared__ double red[8];
  const int t = threadIdx.x;
  h4[t] = 0; h4[t + 1024] = 0;
  __syncthreads();
  const float* idxp = out + OUT_IDX;
  int* const myh = &h4[(t & 3) * 512];
  for (int i = t; i < 65536; i += 1024) {
    int k = (int)idxp[i];
    atomicAdd(&myh[k], 1);
  }
  __syncthreads();
  if (t < 512) {
    int cnt = h4[t] + h4[512 + t] + h4[1024 + t] + h4[1536 + t];
    double p = (double)cnt * (1.0 / 65536.0);
    double term = p * log(p + 1e-10);
    for (int d = 1; d < 64; d <<= 1) term += __shfl_xor(term, d);
    if ((t & 63) == 0) red[t >> 6] = term;
  }
  __syncthreads();
  if (t == 0) {
    double s = 0.0;
    for (int i = 0; i < 8; ++i) s += red[i];
    out[OUT_PERP] = (float)exp(-s);
  }
  if (t < 64) {
    float m = sumsq[t] * (1.0f / 65536.0f);   // exact /2^16
    out[OUT_LOSS + t] = m + 0.25f * m;        // fl(m + fl(0.25m)), numpy order
  }
}

// ---------------------------------------------------------------------------
extern "C" void kernel_launch(void* const* d_in, const int* in_sizes, int n_in,
                              void* d_out, int out_size, void* d_ws, size_t ws_size,
                              hipStream_t stream) {
  const float* x = (const float*)d_in[0];   // [B,C,H,W] fp32
  const float* w = (const float*)d_in[1];   // [K,C] fp32
  float* out = (float*)d_out;
  char* ws = (char*)d_ws;
  float* wt2   = (float*)(ws + WS_WT2);
  float* wnorm = (float*)(ws + WS_WNORM);
  float* sumsq = (float*)(ws + WS_SUMSQ);

  vq_prep<<<128, 256, 0, stream>>>(w, wt2, wnorm, sumsq);
  vq_main<<<2048, 256, 0, stream>>>(x, w, wt2, wnorm, out, sumsq);
  vq_fin<<<1, 1024, 0, stream>>>(out, sumsq);
}